// Round 7
// baseline (518.111 us; speedup 1.0000x reference)
//
#include <hip/hip_runtime.h>

#define N 8192
#define DIN 128
#define DH 48
#define MT 128           // rows per k_gat block (4 waves x 32 rows)
#define KC 64            // j-chunk
#define NSPLIT 8
#define JSPAN (N / NSPLIT)   // 1024
#define NCHUNK (JSPAN / KC)  // 16
#define NW64 (N / 64)        // mask words per row
#define ACC_STRIDE 64    // 48 dims + lsum@48 + pad
#define HSTR 49
#define RB 32            // rows per k_mlp block

typedef _Float16 half8 __attribute__((ext_vector_type(8)));
typedef float f32x4 __attribute__((ext_vector_type(4)));

// ---------------- Kernel 0: pack adj (268 MB, streamed LINEARLY at full HBM BW)
// into a 1-bit mask (8 MB). Lane i reads adj[base+i] -> wave reads 256 B
// contiguous; __ballot packs 64 ints into one uint64 = one mask word.
__global__ __launch_bounds__(256) void k_pack(const int* __restrict__ adj,
                                              unsigned long long* __restrict__ mask) {
    int t = threadIdx.x;
    int lane = t & 63, w = t >> 6;
    size_t wid = (size_t)blockIdx.x * 4 + w;       // wave id; 16384 waves
    size_t base = wid * 64;                        // first mask word of this wave
    const int* src = adj + base * 64 + lane;
    #pragma unroll 4
    for (int k = 0; k < 64; ++k) {
        int v = src[(size_t)k * 64];
        unsigned long long b = __ballot(v != 0);
        if (lane == 0) mask[base + k] = b;
    }
}

// ---------------- Kernel 1a: Wh = x @ Wgat^T  [8192,128]x[48,128] -> [8192,48]
__global__ __launch_bounds__(256) void k_wh(const float* __restrict__ x,
                                            const float* __restrict__ Wg,
                                            float* __restrict__ Wh) {
    __shared__ float wT[DIN * DH];  // wT[k*DH + c] = Wg[c*DIN + k]
    int t = threadIdx.x;
    for (int e = t; e < DIN * DH; e += 256) {
        int c = e / DIN, k = e % DIN;
        wT[k * DH + c] = Wg[e];
    }
    __syncthreads();
    int o = blockIdx.x * 256 + t;
    int r = o / DH, c = o % DH;
    const float4* xr = (const float4*)(x + (size_t)r * DIN);
    float acc = 0.f;
    #pragma unroll 8
    for (int k4 = 0; k4 < DIN / 4; ++k4) {
        float4 xv = xr[k4];
        int kb = k4 * 4;
        acc += xv.x * wT[(kb + 0) * DH + c];
        acc += xv.y * wT[(kb + 1) * DH + c];
        acc += xv.z * wT[(kb + 2) * DH + c];
        acc += xv.w * wT[(kb + 3) * DH + c];
    }
    Wh[o] = acc;
}

// ---------------- Kernel 1b: s = Wh @ a^T
__global__ __launch_bounds__(256) void k_s(const float* __restrict__ Wh,
                                           const float* __restrict__ a,
                                           float* __restrict__ s) {
    int r = blockIdx.x * 256 + threadIdx.x;
    const float4* wr = (const float4*)(Wh + (size_t)r * DH);
    const float4* av = (const float4*)a;
    float acc = 0.f;
    #pragma unroll
    for (int k4 = 0; k4 < DH / 4; ++k4) {
        float4 w = wr[k4]; float4 aa = av[k4];
        acc += w.x * aa.x + w.y * aa.y + w.z * aa.z + w.w * aa.w;
    }
    s[r] = acc;
}

// ---------------- Kernel 1c: WhT16[c][r] = (f16)Wh[r][c]  (B operand source)
__global__ __launch_bounds__(256) void k_tr(const float* __restrict__ Wh,
                                            _Float16* __restrict__ WhT) {
    __shared__ _Float16 tile[DH][72];
    int t = threadIdx.x;
    int r0 = blockIdx.x * 64;
    for (int e = t; e < 64 * DH; e += 256) {
        int r = e / DH, c = e % DH;
        tile[c][r] = (_Float16)Wh[(size_t)(r0 + r) * DH + c];
    }
    __syncthreads();
    for (int u = t; u < DH * 8; u += 256) {
        int c = u >> 3, g = u & 7;
        *(half8*)&WhT[(size_t)c * N + r0 + g * 8] = *(const half8*)&tile[c][g * 8];
    }
}

// p helper: 8 masked-softmax numerator values (f16) from an 8-bit edge mask
__device__ inline half8 mk_p(float si, float4 sa, float4 sb, unsigned mb) {
    float e0 = si + sa.x, e1 = si + sa.y, e2 = si + sa.z, e3 = si + sa.w;
    float e4 = si + sb.x, e5 = si + sb.y, e6 = si + sb.z, e7 = si + sb.w;
    e0 = fmaxf(e0, 0.2f * e0); e1 = fmaxf(e1, 0.2f * e1);
    e2 = fmaxf(e2, 0.2f * e2); e3 = fmaxf(e3, 0.2f * e3);
    e4 = fmaxf(e4, 0.2f * e4); e5 = fmaxf(e5, 0.2f * e5);
    e6 = fmaxf(e6, 0.2f * e6); e7 = fmaxf(e7, 0.2f * e7);
    half8 r;
    r[0] = (_Float16)((mb & 1u)   ? __expf(e0) : 0.f);
    r[1] = (_Float16)((mb & 2u)   ? __expf(e1) : 0.f);
    r[2] = (_Float16)((mb & 4u)   ? __expf(e2) : 0.f);
    r[3] = (_Float16)((mb & 8u)   ? __expf(e3) : 0.f);
    r[4] = (_Float16)((mb & 16u)  ? __expf(e4) : 0.f);
    r[5] = (_Float16)((mb & 32u)  ? __expf(e5) : 0.f);
    r[6] = (_Float16)((mb & 64u)  ? __expf(e6) : 0.f);
    r[7] = (_Float16)((mb & 128u) ? __expf(e7) : 0.f);
    return r;
}

// ---------------- Kernel 2: fused masked-softmax attention, f16 MFMA,
// zero LDS / zero barriers, BITMASK edges. Per thread-chunk: 2 uint64 mask
// words (one per row), 4 float4 of s, 6 half8 B-frags (L2-resident WhT);
// A-frag p computed in registers; bit k of the mask word aligns exactly
// with A[k = kq*8+i]. HBM traffic: 8 MB mask instead of 268 MB adj.
__global__ __launch_bounds__(256, 4) void k_gat(const unsigned long long* __restrict__ mask,
                                                const _Float16* __restrict__ WhT,
                                                const float* __restrict__ s,
                                                float* __restrict__ accWs) {
    int t = threadIdx.x;
    int tile = blockIdx.x & 63;        // 64 row tiles of 128
    int split = blockIdx.x >> 6;       // 0..NSPLIT-1
    int i0 = tile * MT;
    int jbase = split * JSPAN;

    int lane = t & 63, w = t >> 6;
    int ln16 = lane & 15, kq = lane >> 4;   // MFMA lane decomposition

    // constant B-frag, N-tile 3: col 48 = ones (softmax denom), rest 0
    half8 bc;
    {
        _Float16 v = (ln16 == 0) ? (_Float16)1.0f : (_Float16)0.0f;
        #pragma unroll
        for (int i = 0; i < 8; ++i) bc[i] = v;
    }

    f32x4 acc[2][4];
    #pragma unroll
    for (int m = 0; m < 2; ++m)
        #pragma unroll
        for (int n = 0; n < 4; ++n) acc[m][n] = (f32x4){0.f, 0.f, 0.f, 0.f};

    const int row0 = i0 + w * 32 + ln16;     // mtl=0 row
    const int row1 = row0 + 16;              // mtl=1 row
    const float si0 = s[row0];
    const float si1 = s[row1];
    const unsigned long long* mr0 = mask + (size_t)row0 * NW64 + (jbase >> 6);
    const unsigned long long* mr1 = mask + (size_t)row1 * NW64 + (jbase >> 6);

    for (int chunk = 0; chunk < NCHUNK; ++chunk) {
        const int j0 = jbase + chunk * KC;
        const int jk0 = j0 + kq * 8;         // kt=0 k-segment
        const int jk1 = jk0 + 32;            // kt=1 k-segment

        // ---- issue all chunk loads (12 vmem, independent)
        unsigned long long mw0 = mr0[chunk];
        unsigned long long mw1 = mr1[chunk];
        float4 s0a = *(const float4*)(s + jk0);
        float4 s0b = *(const float4*)(s + jk0 + 4);
        float4 s1a = *(const float4*)(s + jk1);
        float4 s1b = *(const float4*)(s + jk1 + 4);
        half8 bf00 = *(const half8*)&WhT[(size_t)(0  + ln16) * N + jk0];
        half8 bf01 = *(const half8*)&WhT[(size_t)(16 + ln16) * N + jk0];
        half8 bf02 = *(const half8*)&WhT[(size_t)(32 + ln16) * N + jk0];
        half8 bf10 = *(const half8*)&WhT[(size_t)(0  + ln16) * N + jk1];
        half8 bf11 = *(const half8*)&WhT[(size_t)(16 + ln16) * N + jk1];
        half8 bf12 = *(const half8*)&WhT[(size_t)(32 + ln16) * N + jk1];

        unsigned b00 = (unsigned)(mw0 >> (kq * 8)) & 0xffu;        // row0, kt0
        unsigned b01 = (unsigned)(mw0 >> (kq * 8 + 32)) & 0xffu;   // row0, kt1
        unsigned b10 = (unsigned)(mw1 >> (kq * 8)) & 0xffu;        // row1, kt0
        unsigned b11 = (unsigned)(mw1 >> (kq * 8 + 32)) & 0xffu;   // row1, kt1

        // ---- A-frags in registers
        half8 a00 = mk_p(si0, s0a, s0b, b00);
        half8 a01 = mk_p(si0, s1a, s1b, b01);
        half8 a10 = mk_p(si1, s0a, s0b, b10);
        half8 a11 = mk_p(si1, s1a, s1b, b11);

        // ---- MFMAs
        acc[0][0] = __builtin_amdgcn_mfma_f32_16x16x32_f16(a00, bf00, acc[0][0], 0, 0, 0);
        acc[0][1] = __builtin_amdgcn_mfma_f32_16x16x32_f16(a00, bf01, acc[0][1], 0, 0, 0);
        acc[0][2] = __builtin_amdgcn_mfma_f32_16x16x32_f16(a00, bf02, acc[0][2], 0, 0, 0);
        acc[0][3] = __builtin_amdgcn_mfma_f32_16x16x32_f16(a00, bc,   acc[0][3], 0, 0, 0);
        acc[1][0] = __builtin_amdgcn_mfma_f32_16x16x32_f16(a10, bf00, acc[1][0], 0, 0, 0);
        acc[1][1] = __builtin_amdgcn_mfma_f32_16x16x32_f16(a10, bf01, acc[1][1], 0, 0, 0);
        acc[1][2] = __builtin_amdgcn_mfma_f32_16x16x32_f16(a10, bf02, acc[1][2], 0, 0, 0);
        acc[1][3] = __builtin_amdgcn_mfma_f32_16x16x32_f16(a10, bc,   acc[1][3], 0, 0, 0);
        acc[0][0] = __builtin_amdgcn_mfma_f32_16x16x32_f16(a01, bf10, acc[0][0], 0, 0, 0);
        acc[0][1] = __builtin_amdgcn_mfma_f32_16x16x32_f16(a01, bf11, acc[0][1], 0, 0, 0);
        acc[0][2] = __builtin_amdgcn_mfma_f32_16x16x32_f16(a01, bf12, acc[0][2], 0, 0, 0);
        acc[0][3] = __builtin_amdgcn_mfma_f32_16x16x32_f16(a01, bc,   acc[0][3], 0, 0, 0);
        acc[1][0] = __builtin_amdgcn_mfma_f32_16x16x32_f16(a11, bf10, acc[1][0], 0, 0, 0);
        acc[1][1] = __builtin_amdgcn_mfma_f32_16x16x32_f16(a11, bf11, acc[1][1], 0, 0, 0);
        acc[1][2] = __builtin_amdgcn_mfma_f32_16x16x32_f16(a11, bf12, acc[1][2], 0, 0, 0);
        acc[1][3] = __builtin_amdgcn_mfma_f32_16x16x32_f16(a11, bc,   acc[1][3], 0, 0, 0);
    }

    // ---- epilogue: C/D layout col=lane&15, row=kq*4+reg; per-split partials
    #pragma unroll
    for (int mtl = 0; mtl < 2; ++mtl) {
        size_t rbase = (size_t)split * N + i0 + w * 32 + mtl * 16 + kq * 4;
        #pragma unroll
        for (int nt = 0; nt < 4; ++nt) {
            int col = nt * 16 + ln16;
            if (nt == 3 && ln16 != 0) continue;   // only col 48 (lsum) useful
            #pragma unroll
            for (int reg = 0; reg < 4; ++reg)
                accWs[(rbase + reg) * ACC_STRIDE + col] = acc[mtl][nt][reg];
        }
    }
}

// ---------------- Kernel 3: reduce splits + LayerNorm + MLP 48->256->128->32
__global__ __launch_bounds__(256) void k_mlp(const float* __restrict__ accWs,
                                             const float* __restrict__ gamma,
                                             const float* __restrict__ beta,
                                             const float* __restrict__ W1, const float* __restrict__ b1,
                                             const float* __restrict__ W2, const float* __restrict__ b2,
                                             const float* __restrict__ W3, const float* __restrict__ b3,
                                             float* __restrict__ out) {
    __shared__ float hs[RB * HSTR];
    __shared__ float hN[RB * DH];
    __shared__ float h1[RB * 256];
    __shared__ float h2[RB * 128];
    int t = threadIdx.x;
    int r0 = blockIdx.x * RB;

    for (int e = t; e < RB * HSTR; e += 256) {
        int r = e / HSTR, d = e % HSTR;
        size_t base = (size_t)(r0 + r) * ACC_STRIDE + d;
        float v = 0.f;
        #pragma unroll
        for (int sp = 0; sp < NSPLIT; ++sp)
            v += accWs[(size_t)sp * N * ACC_STRIDE + base];
        hs[e] = v;
    }
    __syncthreads();

    // LayerNorm (two-pass), h' = acc / l
    if (t < RB) {
        float invl = 1.f / hs[t * HSTR + 48];
        float sum = 0.f;
        for (int d = 0; d < DH; ++d) sum += hs[t * HSTR + d];
        float mean = sum * invl * (1.f / DH);
        float var = 0.f;
        for (int d = 0; d < DH; ++d) {
            float dv = hs[t * HSTR + d] * invl - mean;
            var += dv * dv;
        }
        var *= (1.f / DH);
        float rs = rsqrtf(var + 1e-5f);
        for (int d = 0; d < DH; ++d) {
            float hv = (hs[t * HSTR + d] * invl - mean) * rs;
            hN[t * DH + d] = hv * gamma[d] + beta[d];
        }
    }
    __syncthreads();

    // MLP1: 48 -> 256; thread = 2 cols x 16 rows, W1 cols in VGPRs
    {
        int c0 = (t & 127) * 2, c1 = c0 + 1;
        int rbeg = (t >> 7) * 16;
        float4 wa[12], wb[12];
        const float4* wr0 = (const float4*)(W1 + c0 * DH);
        const float4* wr1 = (const float4*)(W1 + c1 * DH);
        #pragma unroll
        for (int k4 = 0; k4 < 12; ++k4) { wa[k4] = wr0[k4]; wb[k4] = wr1[k4]; }
        float ba = b1[c0], bb = b1[c1];
        for (int r = rbeg; r < rbeg + 16; ++r) {
            const float4* hv4 = (const float4*)&hN[r * DH];
            float a0 = ba, a1 = bb;
            #pragma unroll
            for (int k4 = 0; k4 < 12; ++k4) {
                float4 hv = hv4[k4];
                a0 += hv.x * wa[k4].x + hv.y * wa[k4].y + hv.z * wa[k4].z + hv.w * wa[k4].w;
                a1 += hv.x * wb[k4].x + hv.y * wb[k4].y + hv.z * wb[k4].z + hv.w * wb[k4].w;
            }
            h1[r * 256 + c0] = fmaxf(a0, 0.f);
            h1[r * 256 + c1] = fmaxf(a1, 0.f);
        }
    }
    __syncthreads();

    // MLP2: 256 -> 128; thread = 4 cols x 4 rows
    {
        int c4 = (t & 31) * 4;
        int rr0 = (t >> 5) * 4;
        float a[4][4];
        #pragma unroll
        for (int rr = 0; rr < 4; ++rr)
            #pragma unroll
            for (int cc = 0; cc < 4; ++cc) a[rr][cc] = 0.f;
        for (int k4 = 0; k4 < 64; ++k4) {
            float4 h[4], wv[4];
            #pragma unroll
            for (int rr = 0; rr < 4; ++rr)
                h[rr] = *(const float4*)&h1[(rr0 + rr) * 256 + 4 * k4];
            #pragma unroll
            for (int cc = 0; cc < 4; ++cc)
                wv[cc] = *(const float4*)&W2[(size_t)(c4 + cc) * 256 + 4 * k4];
            #pragma unroll
            for (int rr = 0; rr < 4; ++rr)
                #pragma unroll
                for (int cc = 0; cc < 4; ++cc)
                    a[rr][cc] += h[rr].x * wv[cc].x + h[rr].y * wv[cc].y
                               + h[rr].z * wv[cc].z + h[rr].w * wv[cc].w;
        }
        #pragma unroll
        for (int rr = 0; rr < 4; ++rr)
            #pragma unroll
            for (int cc = 0; cc < 4; ++cc)
                h2[(rr0 + rr) * 128 + c4 + cc] = fmaxf(a[rr][cc] + b2[c4 + cc], 0.f);
    }
    __syncthreads();

    // MLP3: 128 -> 32; thread = 1 col x 4 rows
    {
        int c = t & 31;
        int rr0 = (t >> 5) * 4;
        float a[4];
        float bias = b3[c];
        #pragma unroll
        for (int rr = 0; rr < 4; ++rr) a[rr] = bias;
        const float4* wrow = (const float4*)(W3 + c * 128);
        for (int k4 = 0; k4 < 32; ++k4) {
            float4 wv = wrow[k4];
            #pragma unroll
            for (int rr = 0; rr < 4; ++rr) {
                float4 hv = *(const float4*)&h2[(rr0 + rr) * 128 + 4 * k4];
                a[rr] += wv.x * hv.x + wv.y * hv.y + wv.z * hv.z + wv.w * hv.w;
            }
        }
        #pragma unroll
        for (int rr = 0; rr < 4; ++rr)
            out[(size_t)(r0 + rr0 + rr) * 32 + c] = a[rr];
    }
}

extern "C" void kernel_launch(void* const* d_in, const int* in_sizes, int n_in,
                              void* d_out, int out_size, void* d_ws, size_t ws_size,
                              hipStream_t stream) {
    const float* x     = (const float*)d_in[0];
    const int*   adj   = (const int*)d_in[1];
    const float* Wg    = (const float*)d_in[2];
    const float* a     = (const float*)d_in[3];
    const float* gamma = (const float*)d_in[4];
    const float* beta  = (const float*)d_in[5];
    const float* W1    = (const float*)d_in[6];
    const float* b1    = (const float*)d_in[7];
    const float* W2    = (const float*)d_in[8];
    const float* b2    = (const float*)d_in[9];
    const float* W3    = (const float*)d_in[10];
    const float* b3    = (const float*)d_in[11];
    float* out = (float*)d_out;

    float* ws = (float*)d_ws;
    float*              Wh    = ws;                          // 393216 f32
    float*              s     = Wh + (size_t)N * DH;         // 8192 f32
    _Float16*           WhT   = (_Float16*)(s + N);          // 393216 f16 (=196608 f32)
    unsigned long long* mask  = (unsigned long long*)(WhT + (size_t)N * DH); // 1M u64 = 8 MB
    float*              accWs = (float*)(mask + (size_t)N * NW64);           // 8*N*64 f32

    k_pack<<<N * N / 64 / 256, 256, 0, stream>>>(adj, mask);
    k_wh<<<N * DH / 256, 256, 0, stream>>>(x, Wg, Wh);
    k_s<<<N / 256, 256, 0, stream>>>(Wh, a, s);
    k_tr<<<N / 64, 256, 0, stream>>>(Wh, WhT);
    k_gat<<<64 * NSPLIT, 256, 0, stream>>>(mask, WhT, s, accWs);
    k_mlp<<<N / RB, 256, 0, stream>>>(accWs, gamma, beta, W1, b1, W2, b2, W3, b3, out);
}

// Round 8
// 509.603 us; speedup vs baseline: 1.0167x; 1.0167x over previous
//
#include <hip/hip_runtime.h>

#define N 8192
#define DIN 128
#define DH 48
#define MT 128           // rows per k_gat block (4 waves)
#define KC 64            // j-chunk
#define PSTR 72          // LDS row stride (halves): 144 B -> 2-way bank aliasing
#define NSPLIT 16
#define JSPAN (N / NSPLIT)   // 512
#define NCHUNK (JSPAN / KC)  // 8
#define NW64 (N / 64)        // mask words per row (128)
#define ACC_STRIDE 64    // 48 dims + lsum@48 + pad
#define HSTR 49
#define RB 32            // rows per k_mlp block

typedef _Float16 half8 __attribute__((ext_vector_type(8)));
typedef float f32x4 __attribute__((ext_vector_type(4)));

// ---------------- Kernel 0: pack adj (268 MB, linear full-BW stream) into
// 1-bit mask (8 MB). mask[row*128 + jw] bit b = adj[row*N + jw*64 + b].
__global__ __launch_bounds__(256) void k_pack(const int* __restrict__ adj,
                                              unsigned long long* __restrict__ mask) {
    int t = threadIdx.x;
    int lane = t & 63, w = t >> 6;
    size_t wid = (size_t)blockIdx.x * 4 + w;
    size_t base = wid * 64;
    const int* src = adj + base * 64 + lane;
    #pragma unroll 4
    for (int k = 0; k < 64; ++k) {
        int v = src[(size_t)k * 64];
        unsigned long long b = __ballot(v != 0);
        if (lane == 0) mask[base + k] = b;
    }
}

// ---------------- Kernel 1a: Wh = x @ Wgat^T
__global__ __launch_bounds__(256) void k_wh(const float* __restrict__ x,
                                            const float* __restrict__ Wg,
                                            float* __restrict__ Wh) {
    __shared__ float wT[DIN * DH];
    int t = threadIdx.x;
    for (int e = t; e < DIN * DH; e += 256) {
        int c = e / DIN, k = e % DIN;
        wT[k * DH + c] = Wg[e];
    }
    __syncthreads();
    int o = blockIdx.x * 256 + t;
    int r = o / DH, c = o % DH;
    const float4* xr = (const float4*)(x + (size_t)r * DIN);
    float acc = 0.f;
    #pragma unroll 8
    for (int k4 = 0; k4 < DIN / 4; ++k4) {
        float4 xv = xr[k4];
        int kb = k4 * 4;
        acc += xv.x * wT[(kb + 0) * DH + c];
        acc += xv.y * wT[(kb + 1) * DH + c];
        acc += xv.z * wT[(kb + 2) * DH + c];
        acc += xv.w * wT[(kb + 3) * DH + c];
    }
    Wh[o] = acc;
}

// ---------------- Kernel 1b: s = Wh @ a^T
__global__ __launch_bounds__(256) void k_s(const float* __restrict__ Wh,
                                           const float* __restrict__ a,
                                           float* __restrict__ s) {
    int r = blockIdx.x * 256 + threadIdx.x;
    const float4* wr = (const float4*)(Wh + (size_t)r * DH);
    const float4* av = (const float4*)a;
    float acc = 0.f;
    #pragma unroll
    for (int k4 = 0; k4 < DH / 4; ++k4) {
        float4 w = wr[k4]; float4 aa = av[k4];
        acc += w.x * aa.x + w.y * aa.y + w.z * aa.z + w.w * aa.w;
    }
    s[r] = acc;
}

// p helper: 8 masked-softmax numerators (f16) from an 8-bit edge mask
__device__ inline half8 mk_p(float si, float4 sa, float4 sb, unsigned mb) {
    float e0 = si + sa.x, e1 = si + sa.y, e2 = si + sa.z, e3 = si + sa.w;
    float e4 = si + sb.x, e5 = si + sb.y, e6 = si + sb.z, e7 = si + sb.w;
    e0 = fmaxf(e0, 0.2f * e0); e1 = fmaxf(e1, 0.2f * e1);
    e2 = fmaxf(e2, 0.2f * e2); e3 = fmaxf(e3, 0.2f * e3);
    e4 = fmaxf(e4, 0.2f * e4); e5 = fmaxf(e5, 0.2f * e5);
    e6 = fmaxf(e6, 0.2f * e6); e7 = fmaxf(e7, 0.2f * e7);
    half8 r;
    r[0] = (_Float16)((mb & 1u)   ? __expf(e0) : 0.f);
    r[1] = (_Float16)((mb & 2u)   ? __expf(e1) : 0.f);
    r[2] = (_Float16)((mb & 4u)   ? __expf(e2) : 0.f);
    r[3] = (_Float16)((mb & 8u)   ? __expf(e3) : 0.f);
    r[4] = (_Float16)((mb & 16u)  ? __expf(e4) : 0.f);
    r[5] = (_Float16)((mb & 32u)  ? __expf(e5) : 0.f);
    r[6] = (_Float16)((mb & 64u)  ? __expf(e6) : 0.f);
    r[7] = (_Float16)((mb & 128u) ? __expf(e7) : 0.f);
    return r;
}

// ---------------- Kernel 2: fused masked-softmax attention, f16 MFMA,
// r3's LDS structure + bitmask edges. Per 64-j chunk:
//   [stage wS from row-major Wh (coalesced) ; phase A: thread=(row, 32-j half),
//    1 mask word + 8 L1-shared s-loads -> p in regs -> 4x ds_write_b128]
//   barrier [MFMA: 16/wave, B from wS broadcast, ones-col for denom] barrier.
// No strided adj loads, no LDS read-after-write within a phase.
__global__ __launch_bounds__(256, 4) void k_gat(const unsigned long long* __restrict__ mask,
                                                const float* __restrict__ Wh,
                                                const float* __restrict__ s,
                                                float* __restrict__ accWs) {
    __shared__ _Float16 pS[MT][PSTR];   // A: P[row][j]
    __shared__ _Float16 wS[64][PSTR];   // B^T: wS[d][j]; rows 48..63 zero
    int t = threadIdx.x;
    int tile = blockIdx.x & 63;        // 64 row tiles of 128
    int split = blockIdx.x >> 6;       // 0..15
    int i0 = tile * MT;
    int jbase = split * JSPAN;
    int jw0 = jbase >> 6;              // first mask word of this split

    int lane = t & 63, w = t >> 6;
    int ln16 = lane & 15, kq = lane >> 4;   // MFMA lane decomposition
    int prow = t >> 1, ph = t & 1;          // phase A: row, 32-j half

    // zero pad rows of wS (d=48..63) once
    for (int e = t; e < 16 * PSTR; e += 256)
        wS[48 + e / PSTR][e % PSTR] = (_Float16)0.0f;

    // constant B-frag, N-tile 3: col 48 = ones (softmax denom), rest 0
    half8 bc;
    {
        _Float16 v = (ln16 == 0) ? (_Float16)1.0f : (_Float16)0.0f;
        #pragma unroll
        for (int i = 0; i < 8; ++i) bc[i] = v;
    }

    f32x4 acc[2][4];
    #pragma unroll
    for (int m = 0; m < 2; ++m)
        #pragma unroll
        for (int n = 0; n < 4; ++n) acc[m][n] = (f32x4){0.f, 0.f, 0.f, 0.f};

    const float si = s[i0 + prow];     // own row's score, in register
    const unsigned long long* mrow = mask + (size_t)(i0 + prow) * NW64 + jw0;

    __syncthreads();                   // wS pad init visible

    for (int chunk = 0; chunk < NCHUNK; ++chunk) {
        const int j0 = jbase + chunk * KC;
        // ---- stage Wh chunk -> wS (coalesced float reads, f16 transpose write)
        {
            const float* wsrc = Wh + (size_t)j0 * DH;
            #pragma unroll
            for (int k = 0; k < 12; ++k) {
                int e = t + k * 256;            // e < 3072 = 64*48
                int jc = e / DH, d = e % DH;
                wS[d][jc] = (_Float16)wsrc[e];
            }
        }
        // ---- phase A: p for own row, 32 j (1 mask word, s from L1)
        {
            unsigned long long mw = mrow[chunk];
            #pragma unroll
            for (int g = 0; g < 4; ++g) {
                int jo = ph * 32 + g * 8;
                float4 sa = *(const float4*)(s + j0 + jo);
                float4 sb = *(const float4*)(s + j0 + jo + 4);
                unsigned mb = (unsigned)(mw >> jo) & 0xffu;
                half8 pv = mk_p(si, sa, sb, mb);
                *(half8*)&pS[prow][jo] = pv;
            }
        }
        __syncthreads();
        // ---- MFMA: wave w owns M-tiles 2w..2w+1; N-tiles 0..2 + ones col
        {
            int m0 = w * 32;
            #pragma unroll
            for (int kt = 0; kt < 2; ++kt) {
                int kk = kt * 32 + kq * 8;
                half8 b0 = *(const half8*)&wS[0  + ln16][kk];
                half8 b1 = *(const half8*)&wS[16 + ln16][kk];
                half8 b2 = *(const half8*)&wS[32 + ln16][kk];
                #pragma unroll
                for (int mtl = 0; mtl < 2; ++mtl) {
                    half8 a = *(const half8*)&pS[m0 + mtl * 16 + ln16][kk];
                    acc[mtl][0] = __builtin_amdgcn_mfma_f32_16x16x32_f16(a, b0, acc[mtl][0], 0, 0, 0);
                    acc[mtl][1] = __builtin_amdgcn_mfma_f32_16x16x32_f16(a, b1, acc[mtl][1], 0, 0, 0);
                    acc[mtl][2] = __builtin_amdgcn_mfma_f32_16x16x32_f16(a, b2, acc[mtl][2], 0, 0, 0);
                    acc[mtl][3] = __builtin_amdgcn_mfma_f32_16x16x32_f16(a, bc, acc[mtl][3], 0, 0, 0);
                }
            }
        }
        __syncthreads();
    }

    // ---- epilogue: C/D layout col=lane&15, row=kq*4+reg; per-split partials
    #pragma unroll
    for (int mtl = 0; mtl < 2; ++mtl) {
        size_t rbase = (size_t)split * N + i0 + w * 32 + mtl * 16 + kq * 4;
        #pragma unroll
        for (int nt = 0; nt < 4; ++nt) {
            int col = nt * 16 + ln16;
            if (nt == 3 && ln16 != 0) continue;   // only col 48 (lsum) useful
            #pragma unroll
            for (int reg = 0; reg < 4; ++reg)
                accWs[(rbase + reg) * ACC_STRIDE + col] = acc[mtl][nt][reg];
        }
    }
}

// ---------------- Kernel 3: reduce splits + LayerNorm + MLP 48->256->128->32
__global__ __launch_bounds__(256) void k_mlp(const float* __restrict__ accWs,
                                             const float* __restrict__ gamma,
                                             const float* __restrict__ beta,
                                             const float* __restrict__ W1, const float* __restrict__ b1,
                                             const float* __restrict__ W2, const float* __restrict__ b2,
                                             const float* __restrict__ W3, const float* __restrict__ b3,
                                             float* __restrict__ out) {
    __shared__ float hs[RB * HSTR];
    __shared__ float hN[RB * DH];
    __shared__ float h1[RB * 256];
    __shared__ float h2[RB * 128];
    int t = threadIdx.x;
    int r0 = blockIdx.x * RB;

    for (int e = t; e < RB * HSTR; e += 256) {
        int r = e / HSTR, d = e % HSTR;
        size_t base = (size_t)(r0 + r) * ACC_STRIDE + d;
        float v = 0.f;
        #pragma unroll
        for (int sp = 0; sp < NSPLIT; ++sp)
            v += accWs[(size_t)sp * N * ACC_STRIDE + base];
        hs[e] = v;
    }
    __syncthreads();

    if (t < RB) {
        float invl = 1.f / hs[t * HSTR + 48];
        float sum = 0.f;
        for (int d = 0; d < DH; ++d) sum += hs[t * HSTR + d];
        float mean = sum * invl * (1.f / DH);
        float var = 0.f;
        for (int d = 0; d < DH; ++d) {
            float dv = hs[t * HSTR + d] * invl - mean;
            var += dv * dv;
        }
        var *= (1.f / DH);
        float rs = rsqrtf(var + 1e-5f);
        for (int d = 0; d < DH; ++d) {
            float hv = (hs[t * HSTR + d] * invl - mean) * rs;
            hN[t * DH + d] = hv * gamma[d] + beta[d];
        }
    }
    __syncthreads();

    // MLP1: 48 -> 256; thread = 2 cols x 16 rows, W1 cols in VGPRs
    {
        int c0 = (t & 127) * 2, c1 = c0 + 1;
        int rbeg = (t >> 7) * 16;
        float4 wa[12], wb[12];
        const float4* wr0 = (const float4*)(W1 + c0 * DH);
        const float4* wr1 = (const float4*)(W1 + c1 * DH);
        #pragma unroll
        for (int k4 = 0; k4 < 12; ++k4) { wa[k4] = wr0[k4]; wb[k4] = wr1[k4]; }
        float ba = b1[c0], bb = b1[c1];
        for (int r = rbeg; r < rbeg + 16; ++r) {
            const float4* hv4 = (const float4*)&hN[r * DH];
            float a0 = ba, a1 = bb;
            #pragma unroll
            for (int k4 = 0; k4 < 12; ++k4) {
                float4 hv = hv4[k4];
                a0 += hv.x * wa[k4].x + hv.y * wa[k4].y + hv.z * wa[k4].z + hv.w * wa[k4].w;
                a1 += hv.x * wb[k4].x + hv.y * wb[k4].y + hv.z * wb[k4].z + hv.w * wb[k4].w;
            }
            h1[r * 256 + c0] = fmaxf(a0, 0.f);
            h1[r * 256 + c1] = fmaxf(a1, 0.f);
        }
    }
    __syncthreads();

    // MLP2: 256 -> 128; thread = 4 cols x 4 rows
    {
        int c4 = (t & 31) * 4;
        int rr0 = (t >> 5) * 4;
        float a[4][4];
        #pragma unroll
        for (int rr = 0; rr < 4; ++rr)
            #pragma unroll
            for (int cc = 0; cc < 4; ++cc) a[rr][cc] = 0.f;
        for (int k4 = 0; k4 < 64; ++k4) {
            float4 h[4], wv[4];
            #pragma unroll
            for (int rr = 0; rr < 4; ++rr)
                h[rr] = *(const float4*)&h1[(rr0 + rr) * 256 + 4 * k4];
            #pragma unroll
            for (int cc = 0; cc < 4; ++cc)
                wv[cc] = *(const float4*)&W2[(size_t)(c4 + cc) * 256 + 4 * k4];
            #pragma unroll
            for (int rr = 0; rr < 4; ++rr)
                #pragma unroll
                for (int cc = 0; cc < 4; ++cc)
                    a[rr][cc] += h[rr].x * wv[cc].x + h[rr].y * wv[cc].y
                               + h[rr].z * wv[cc].z + h[rr].w * wv[cc].w;
        }
        #pragma unroll
        for (int rr = 0; rr < 4; ++rr)
            #pragma unroll
            for (int cc = 0; cc < 4; ++cc)
                h2[(rr0 + rr) * 128 + c4 + cc] = fmaxf(a[rr][cc] + b2[c4 + cc], 0.f);
    }
    __syncthreads();

    // MLP3: 128 -> 32; thread = 1 col x 4 rows
    {
        int c = t & 31;
        int rr0 = (t >> 5) * 4;
        float a[4];
        float bias = b3[c];
        #pragma unroll
        for (int rr = 0; rr < 4; ++rr) a[rr] = bias;
        const float4* wrow = (const float4*)(W3 + c * 128);
        for (int k4 = 0; k4 < 32; ++k4) {
            float4 wv = wrow[k4];
            #pragma unroll
            for (int rr = 0; rr < 4; ++rr) {
                float4 hv = *(const float4*)&h2[(rr0 + rr) * 128 + 4 * k4];
                a[rr] += wv.x * hv.x + wv.y * hv.y + wv.z * hv.z + wv.w * hv.w;
            }
        }
        #pragma unroll
        for (int rr = 0; rr < 4; ++rr)
            out[(size_t)(r0 + rr0 + rr) * 32 + c] = a[rr];
    }
}

extern "C" void kernel_launch(void* const* d_in, const int* in_sizes, int n_in,
                              void* d_out, int out_size, void* d_ws, size_t ws_size,
                              hipStream_t stream) {
    const float* x     = (const float*)d_in[0];
    const int*   adj   = (const int*)d_in[1];
    const float* Wg    = (const float*)d_in[2];
    const float* a     = (const float*)d_in[3];
    const float* gamma = (const float*)d_in[4];
    const float* beta  = (const float*)d_in[5];
    const float* W1    = (const float*)d_in[6];
    const float* b1    = (const float*)d_in[7];
    const float* W2    = (const float*)d_in[8];
    const float* b2    = (const float*)d_in[9];
    const float* W3    = (const float*)d_in[10];
    const float* b3    = (const float*)d_in[11];
    float* out = (float*)d_out;

    float* ws = (float*)d_ws;
    float*              Wh    = ws;                          // 393216 f32
    float*              s     = Wh + (size_t)N * DH;         // 8192 f32
    unsigned long long* mask  = (unsigned long long*)(s + N);          // 1M u64 = 8 MB
    float*              accWs = (float*)(mask + (size_t)N * NW64);     // 16*N*64 f32

    k_pack<<<N * N / 64 / 256, 256, 0, stream>>>(adj, mask);
    k_wh<<<N * DH / 256, 256, 0, stream>>>(x, Wg, Wh);
    k_s<<<N / 256, 256, 0, stream>>>(Wh, a, s);
    k_gat<<<64 * NSPLIT, 256, 0, stream>>>(mask, Wh, s, accWs);
    k_mlp<<<N / RB, 256, 0, stream>>>(accWs, gamma, beta, W1, b1, W2, b2, W3, b3, out);
}